// Round 5
// baseline (665.652 us; speedup 1.0000x reference)
//
#include <hip/hip_runtime.h>

// GIN fused: msg = node_feat[src] + edge_feat; agg = segment_sum(msg, dst);
// out = relu(agg@w1+b1)@w2+b2.  N=50000, E=800000, H=128.
//
// Round 5: register-tiled fp32 MLP (8x8 / 4x8 thread tiles, weights streamed
// from L2 via pre-transposed copies, A from LDS) -> FMA-bound instead of
// 6x LDS-instruction-bound. Gather reverted to round-3 wave-uniform form.

constexpr int NN = 50000;
constexpr int NE = 800000;
constexpr int H  = 128;   // hidden
constexpr int H2 = 256;   // 2*hidden
constexpr int MT = 64;    // rows per MLP block

// ---------------------------------------------------------------------------
__global__ __launch_bounds__(256) void zero_kernel(int4* __restrict__ p, int n4)
{
    int i = blockIdx.x * blockDim.x + threadIdx.x;
    if (i < n4) p[i] = make_int4(0, 0, 0, 0);
}

// ---------------------------------------------------------------------------
// CSR build step 1: histogram of edge_dst
// ---------------------------------------------------------------------------
__global__ __launch_bounds__(256) void count_kernel(
    const int* __restrict__ edge_dst, int* __restrict__ count)
{
    int e = blockIdx.x * blockDim.x + threadIdx.x;
    if (e < NE) atomicAdd(&count[edge_dst[e]], 1);
}

// ---------------------------------------------------------------------------
// CSR build step 2: exclusive prefix sum over count[NN] -> offsets[NN+1].
// ---------------------------------------------------------------------------
__global__ __launch_bounds__(1024) void scan_kernel(
    const int* __restrict__ count, int* __restrict__ offsets)
{
    __shared__ int sums[1024];
    const int t  = threadIdx.x;
    const int CH = (NN + 1023) / 1024;          // 49
    const int beg = t * CH;
    const int end = (beg + CH < NN) ? beg + CH : NN;
    int s = 0;
    for (int i = beg; i < end; ++i) s += count[i];
    sums[t] = s;
    __syncthreads();
    for (int off = 1; off < 1024; off <<= 1) {
        int v = (t >= off) ? sums[t - off] : 0;
        __syncthreads();
        if (t >= off) sums[t] += v;
        __syncthreads();
    }
    int run = (t == 0) ? 0 : sums[t - 1];       // exclusive prefix
    for (int i = beg; i < end; ++i) { offsets[i] = run; run += count[i]; }
    if (t == 1023) offsets[NN] = run;           // == NE
}

// ---------------------------------------------------------------------------
// CSR build step 3: place (eid, src) pairs grouped by destination
// ---------------------------------------------------------------------------
__global__ __launch_bounds__(256) void place_kernel(
    const int* __restrict__ edge_dst, const int* __restrict__ edge_src,
    const int* __restrict__ offsets,
    int* __restrict__ cursor, int2* __restrict__ sorted_es)
{
    int e = blockIdx.x * blockDim.x + threadIdx.x;
    if (e < NE) {
        int d = edge_dst[e];
        int pos = offsets[d] + atomicAdd(&cursor[d], 1);
        sorted_es[pos] = make_int2(e, edge_src[e]);
    }
}

// ---------------------------------------------------------------------------
// Weight prep: transpose w1 [128][256] -> w1t [256][128] and
//              w2 [256][128] -> w2t [128][256] so the MLP reads weight
// rows as contiguous b128 along k.
// ---------------------------------------------------------------------------
__global__ __launch_bounds__(256) void prep_kernel(
    const float* __restrict__ w1, const float* __restrict__ w2,
    float* __restrict__ w1t, float* __restrict__ w2t)
{
    int i = blockIdx.x * blockDim.x + threadIdx.x;   // 0..32767
    if (i < H * H2) {
        { int k = i >> 8, c = i & 255; w1t[c * H  + k] = w1[i]; }
        { int k = i >> 7, c = i & 127; w2t[c * H2 + k] = w2[i]; }
    }
}

// ---------------------------------------------------------------------------
// Gather (round-3 form): one 64-lane wave per node, float2 per lane,
// wave-uniform (eid,src) loads. No atomics.
// ---------------------------------------------------------------------------
__global__ __launch_bounds__(256) void gather_kernel(
    const float* __restrict__ node_feat,
    const float* __restrict__ edge_feat,
    const int2*  __restrict__ sorted_es,
    const int*   __restrict__ offsets,
    float*       __restrict__ agg)
{
    const int node = blockIdx.x * 4 + (threadIdx.x >> 6);
    const int co   = (threadIdx.x & 63) * 2;
    const int start = offsets[node];
    const int end   = offsets[node + 1];
    float accx = 0.f, accy = 0.f;
    for (int i = start; i < end; ++i) {
        const int2 es = sorted_es[i];         // wave-uniform
        const float2 ef = *(const float2*)(edge_feat + (size_t)es.x * H + co);
        const float2 nf = *(const float2*)(node_feat + (size_t)es.y * H + co);
        accx += ef.x + nf.x;
        accy += ef.y + nf.y;
    }
    float2* dst = (float2*)(agg + (size_t)node * H + co);
    dst->x = accx;
    dst->y = accy;
}

// ---------------------------------------------------------------------------
// MLP, register-tiled fp32.
// Block: 256 threads, MT=64 rows.
// Layer1: thread tile 8 rows x 8 cols (acc 64 VGPR); A from LDS (broadcast,
//   8 b128 per 256 FMA-instr per k4-step -> FMA-bound), W from global (L2).
// Layer2: thread tile 4 rows x 8 cols, h from padded LDS, W from global.
// LDS: s_a[64][128] (32KB) unioned with s_h[64][260] (66.5KB) -> 2 blocks/CU.
// ---------------------------------------------------------------------------
__global__ __launch_bounds__(256) void mlp_kernel(
    const float* __restrict__ agg,
    const float* __restrict__ w1t, const float* __restrict__ b1,
    const float* __restrict__ w2t, const float* __restrict__ b2,
    float*       __restrict__ out)
{
    constexpr int SH_STRIDE = 260;            // s_h row stride (pad vs 256)
    __shared__ float smem[MT * SH_STRIDE];    // 66,560 B

    const int t = threadIdx.x;
    const long long nbase = (long long)blockIdx.x * MT;

    // ---- stage s_a = agg[nbase .. nbase+63][:], zero-pad past NN ----
    {
        const float4* src = (const float4*)(agg + nbase * H);
        const long long rem4 = ((long long)NN - nbase) * (H / 4);
        #pragma unroll
        for (int i = 0; i < 8; ++i) {
            const int idx = t + i * 256;                 // 0..2047
            float4 v = make_float4(0.f, 0.f, 0.f, 0.f);
            if (idx < rem4) v = src[idx];
            *(float4*)&smem[idx * 4] = v;                // s_a[n][k], n=idx/32
        }
    }
    __syncthreads();

    // ---- layer 1: h = relu(A @ w1 + b1) ----
    const int row0 = (t >> 5) * 8;            // 0..56
    const int col0 = (t & 31) * 8;            // 0..248
    float acc[8][8];
    #pragma unroll
    for (int j = 0; j < 8; ++j) {
        const float b = b1[col0 + j];
        #pragma unroll
        for (int i = 0; i < 8; ++i) acc[i][j] = b;
    }
    for (int k4 = 0; k4 < H / 4; ++k4) {
        float4 a[8];
        #pragma unroll
        for (int i = 0; i < 8; ++i)
            a[i] = *(const float4*)&smem[(row0 + i) * H + k4 * 4];  // broadcast
        #pragma unroll
        for (int j = 0; j < 8; ++j) {
            const float4 w = *(const float4*)(w1t + (col0 + j) * H + k4 * 4);
            #pragma unroll
            for (int i = 0; i < 8; ++i) {
                acc[i][j] = fmaf(a[i].x, w.x, acc[i][j]);
                acc[i][j] = fmaf(a[i].y, w.y, acc[i][j]);
                acc[i][j] = fmaf(a[i].z, w.z, acc[i][j]);
                acc[i][j] = fmaf(a[i].w, w.w, acc[i][j]);
            }
        }
    }
    __syncthreads();   // all s_a reads done before s_h overwrites the union

    #pragma unroll
    for (int i = 0; i < 8; ++i) {
        #pragma unroll
        for (int j4 = 0; j4 < 2; ++j4) {
            float4 v;
            v.x = fmaxf(acc[i][j4 * 4 + 0], 0.f);
            v.y = fmaxf(acc[i][j4 * 4 + 1], 0.f);
            v.z = fmaxf(acc[i][j4 * 4 + 2], 0.f);
            v.w = fmaxf(acc[i][j4 * 4 + 3], 0.f);
            *(float4*)&smem[(row0 + i) * SH_STRIDE + col0 + j4 * 4] = v;
        }
    }
    __syncthreads();

    // ---- layer 2: out = h @ w2 + b2 ----
    const int r2 = (t >> 4) * 4;              // 0..60
    const int c2 = (t & 15) * 8;              // 0..120
    float acc2[4][8];
    #pragma unroll
    for (int j = 0; j < 8; ++j) {
        const float b = b2[c2 + j];
        #pragma unroll
        for (int i = 0; i < 4; ++i) acc2[i][j] = b;
    }
    for (int k4 = 0; k4 < H2 / 4; ++k4) {
        float4 a[4];
        #pragma unroll
        for (int i = 0; i < 4; ++i)
            a[i] = *(const float4*)&smem[(r2 + i) * SH_STRIDE + k4 * 4];
        #pragma unroll
        for (int j = 0; j < 8; ++j) {
            const float4 w = *(const float4*)(w2t + (c2 + j) * H2 + k4 * 4);
            #pragma unroll
            for (int i = 0; i < 4; ++i) {
                acc2[i][j] = fmaf(a[i].x, w.x, acc2[i][j]);
                acc2[i][j] = fmaf(a[i].y, w.y, acc2[i][j]);
                acc2[i][j] = fmaf(a[i].z, w.z, acc2[i][j]);
                acc2[i][j] = fmaf(a[i].w, w.w, acc2[i][j]);
            }
        }
    }
    #pragma unroll
    for (int i = 0; i < 4; ++i) {
        const long long n = nbase + r2 + i;
        if (n < NN) {
            #pragma unroll
            for (int j4 = 0; j4 < 2; ++j4) {
                float4 v;
                v.x = acc2[i][j4 * 4 + 0];
                v.y = acc2[i][j4 * 4 + 1];
                v.z = acc2[i][j4 * 4 + 2];
                v.w = acc2[i][j4 * 4 + 3];
                *(float4*)(out + n * H + c2 + j4 * 4) = v;
            }
        }
    }
}

// ---------------------------------------------------------------------------
// Fallback path (tiny workspace): atomic scatter + simple MLP (round-3 form).
// ---------------------------------------------------------------------------
__global__ __launch_bounds__(256) void scatter_kernel(
    const float* __restrict__ node_feat,
    const float* __restrict__ edge_feat,
    const int*   __restrict__ edge_src,
    const int*   __restrict__ edge_dst,
    float*       __restrict__ agg)
{
    long long tid = (long long)blockIdx.x * blockDim.x + threadIdx.x;
    const long long total = (long long)NE * 32;
    if (tid >= total) return;
    int e = (int)(tid >> 5);
    int q = (int)((tid & 31) << 2);
    int s = edge_src[e];
    int d = edge_dst[e];
    const float4 nf = *(const float4*)(node_feat + (long long)s * H + q);
    const float4 ef = *(const float4*)(edge_feat + (long long)e * H + q);
    float* dst = agg + (long long)d * H + q;
    atomicAdd(dst + 0, nf.x + ef.x);
    atomicAdd(dst + 1, nf.y + ef.y);
    atomicAdd(dst + 2, nf.z + ef.z);
    atomicAdd(dst + 3, nf.w + ef.w);
}

__global__ __launch_bounds__(256) void mlp_simple_kernel(
    const float* __restrict__ agg,
    const float* __restrict__ w1, const float* __restrict__ b1,
    const float* __restrict__ w2, const float* __restrict__ b2,
    float*       __restrict__ out)
{
    constexpr int NPB = 16;
    __shared__ float s_in[NPB][H];
    __shared__ float s_h [NPB][H2];
    const int t = threadIdx.x;
    const long long base = (long long)blockIdx.x * NPB;
    {
        const float4* src = (const float4*)(agg + base * H);
        float4* dst = (float4*)(&s_in[0][0]);
        dst[t]       = src[t];
        dst[t + 256] = src[t + 256];
    }
    __syncthreads();
    float acc[NPB];
    {
        const float b = b1[t];
        #pragma unroll
        for (int n = 0; n < NPB; ++n) acc[n] = b;
    }
    #pragma unroll 4
    for (int k = 0; k < H; ++k) {
        const float w = w1[k * H2 + t];
        #pragma unroll
        for (int n = 0; n < NPB; ++n) acc[n] = fmaf(s_in[n][k], w, acc[n]);
    }
    #pragma unroll
    for (int n = 0; n < NPB; ++n) s_h[n][t] = fmaxf(acc[n], 0.0f);
    __syncthreads();
    const int j = t & (H - 1);
    const int g = t >> 7;
    float acc2[NPB / 2];
    {
        const float b = b2[j];
        #pragma unroll
        for (int n = 0; n < NPB / 2; ++n) acc2[n] = b;
    }
    #pragma unroll 4
    for (int k = 0; k < H2; ++k) {
        const float w = w2[k * H + j];
        #pragma unroll
        for (int n = 0; n < NPB / 2; ++n)
            acc2[n] = fmaf(s_h[g * (NPB / 2) + n][k], w, acc2[n]);
    }
    #pragma unroll
    for (int n = 0; n < NPB / 2; ++n)
        out[(base + g * (NPB / 2) + n) * H + j] = acc2[n];
}

__global__ __launch_bounds__(256) void zero_agg_kernel(float4* __restrict__ p, int n4)
{
    int i = blockIdx.x * blockDim.x + threadIdx.x;
    if (i < n4) p[i] = make_float4(0.f, 0.f, 0.f, 0.f);
}

// ---------------------------------------------------------------------------
extern "C" void kernel_launch(void* const* d_in, const int* in_sizes, int n_in,
                              void* d_out, int out_size, void* d_ws, size_t ws_size,
                              hipStream_t stream)
{
    const float* node_feat = (const float*)d_in[0];
    const float* edge_feat = (const float*)d_in[1];
    const int*   edge_src  = (const int*)  d_in[2];
    const int*   edge_dst  = (const int*)  d_in[3];
    const float* w1 = (const float*)d_in[4];
    const float* b1 = (const float*)d_in[5];
    const float* w2 = (const float*)d_in[6];
    const float* b2 = (const float*)d_in[7];
    float* out = (float*)d_out;

    // Workspace layout (256-B aligned regions)
    const size_t count_b  = ((size_t)NN * 4 + 255) & ~(size_t)255;        // 200 KB
    const size_t cursor_b = count_b;                                       // 200 KB
    const size_t offs_b   = (((size_t)NN + 1) * 4 + 255) & ~(size_t)255;   // 200 KB
    const size_t es_b     = ((size_t)NE * 8 + 255) & ~(size_t)255;         // 6.4 MB
    const size_t w1t_b    = (size_t)H * H2 * 4;                            // 128 KB
    const size_t w2t_b    = (size_t)H * H2 * 4;                            // 128 KB
    const size_t agg_b    = (size_t)NN * H * sizeof(float);                // 25.6 MB
    const size_t need     = count_b + cursor_b + offs_b + es_b + w1t_b + w2t_b + agg_b;

    if (ws_size >= need) {
        char* p = (char*)d_ws;
        int*   count     = (int*)p;              p += count_b;
        int*   cursor    = (int*)p;              p += cursor_b;
        int*   offsets   = (int*)p;              p += offs_b;
        int2*  sorted_es = (int2*)p;             p += es_b;
        float* w1t       = (float*)p;            p += w1t_b;
        float* w2t       = (float*)p;            p += w2t_b;
        float* agg       = (float*)p;

        {
            const int n4 = (int)((count_b + cursor_b) / 16);
            zero_kernel<<<(n4 + 255) / 256, 256, 0, stream>>>((int4*)d_ws, n4);
        }

        const int eb = 256, eg = (NE + eb - 1) / eb;   // 3125
        count_kernel<<<eg, eb, 0, stream>>>(edge_dst, count);
        scan_kernel<<<1, 1024, 0, stream>>>(count, offsets);
        place_kernel<<<eg, eb, 0, stream>>>(edge_dst, edge_src, offsets, cursor, sorted_es);
        prep_kernel<<<(H * H2 + 255) / 256, 256, 0, stream>>>(w1, w2, w1t, w2t);
        gather_kernel<<<NN / 4, 256, 0, stream>>>(
            node_feat, edge_feat, sorted_es, offsets, agg);
        mlp_kernel<<<(NN + MT - 1) / MT, 256, 0, stream>>>(
            agg, w1t, b1, w2t, b2, out);
    } else {
        // Fallback: atomic path + simple MLP
        const size_t agg_bytes = (size_t)NN * H * sizeof(float);
        float* agg = (ws_size >= agg_bytes) ? (float*)d_ws : out;
        {
            const int n4 = (int)(agg_bytes / 16);
            zero_agg_kernel<<<(n4 + 255) / 256, 256, 0, stream>>>((float4*)agg, n4);
        }
        const long long total = (long long)NE * 32;
        const int block = 256;
        const int grid  = (int)((total + block - 1) / block);
        scatter_kernel<<<grid, block, 0, stream>>>(
            node_feat, edge_feat, edge_src, edge_dst, agg);
        mlp_simple_kernel<<<NN / 16, 256, 0, stream>>>(agg, w1, b1, w2, b2, out);
    }
}

// Round 6
// 545.113 us; speedup vs baseline: 1.2211x; 1.2211x over previous
//
#include <hip/hip_runtime.h>

// GIN fused: msg = node_feat[src] + edge_feat; agg = segment_sum(msg, dst);
// out = relu(agg@w1+b1)@w2+b2.  N=50000, E=800000, H=128.
//
// Round 6: MLP split into two register-tiled GEMM kernels (no LDS union, no
// spills: __launch_bounds__(256,2), <=115 VGPR need, 32/64 KB LDS).
// Gather: int4 dual-edge wave-uniform prefetch (4 feature loads in flight).

constexpr int NN = 50000;
constexpr int NE = 800000;
constexpr int H  = 128;   // hidden
constexpr int H2 = 256;   // 2*hidden
constexpr int MT = 64;    // rows per GEMM block

// ---------------------------------------------------------------------------
__global__ __launch_bounds__(256) void zero_kernel(int4* __restrict__ p, int n4)
{
    int i = blockIdx.x * blockDim.x + threadIdx.x;
    if (i < n4) p[i] = make_int4(0, 0, 0, 0);
}

// ---------------------------------------------------------------------------
// CSR build step 1: histogram of edge_dst
// ---------------------------------------------------------------------------
__global__ __launch_bounds__(256) void count_kernel(
    const int* __restrict__ edge_dst, int* __restrict__ count)
{
    int e = blockIdx.x * blockDim.x + threadIdx.x;
    if (e < NE) atomicAdd(&count[edge_dst[e]], 1);
}

// ---------------------------------------------------------------------------
// CSR build step 2: exclusive prefix sum over count[NN] -> offsets[NN+1].
// ---------------------------------------------------------------------------
__global__ __launch_bounds__(1024) void scan_kernel(
    const int* __restrict__ count, int* __restrict__ offsets)
{
    __shared__ int sums[1024];
    const int t  = threadIdx.x;
    const int CH = (NN + 1023) / 1024;          // 49
    const int beg = t * CH;
    const int end = (beg + CH < NN) ? beg + CH : NN;
    int s = 0;
    for (int i = beg; i < end; ++i) s += count[i];
    sums[t] = s;
    __syncthreads();
    for (int off = 1; off < 1024; off <<= 1) {
        int v = (t >= off) ? sums[t - off] : 0;
        __syncthreads();
        if (t >= off) sums[t] += v;
        __syncthreads();
    }
    int run = (t == 0) ? 0 : sums[t - 1];       // exclusive prefix
    for (int i = beg; i < end; ++i) { offsets[i] = run; run += count[i]; }
    if (t == 1023) offsets[NN] = run;           // == NE
}

// ---------------------------------------------------------------------------
// CSR build step 3: place (eid, src) pairs grouped by destination
// ---------------------------------------------------------------------------
__global__ __launch_bounds__(256) void place_kernel(
    const int* __restrict__ edge_dst, const int* __restrict__ edge_src,
    const int* __restrict__ offsets,
    int* __restrict__ cursor, int2* __restrict__ sorted_es)
{
    int e = blockIdx.x * blockDim.x + threadIdx.x;
    if (e < NE) {
        int d = edge_dst[e];
        int pos = offsets[d] + atomicAdd(&cursor[d], 1);
        sorted_es[pos] = make_int2(e, edge_src[e]);
    }
}

// ---------------------------------------------------------------------------
// Weight prep: w1 [128][256] -> w1t [256][128]; w2 [256][128] -> w2t [128][256]
// so GEMMs read weight rows contiguously along k.
// ---------------------------------------------------------------------------
__global__ __launch_bounds__(256) void prep_kernel(
    const float* __restrict__ w1, const float* __restrict__ w2,
    float* __restrict__ w1t, float* __restrict__ w2t)
{
    int i = blockIdx.x * blockDim.x + threadIdx.x;   // 0..32767
    if (i < H * H2) {
        { int k = i >> 8, c = i & 255; w1t[c * H  + k] = w1[i]; }
        { int k = i >> 7, c = i & 127; w2t[c * H2 + k] = w2[i]; }
    }
}

// ---------------------------------------------------------------------------
// Gather: one 64-lane wave per node, float2 per lane. Wave-uniform int4 load
// fetches TWO (eid,src) pairs -> 4 independent 512B feature loads in flight.
// ---------------------------------------------------------------------------
__global__ __launch_bounds__(256) void gather_kernel(
    const float* __restrict__ node_feat,
    const float* __restrict__ edge_feat,
    const int2*  __restrict__ sorted_es,
    const int*   __restrict__ offsets,
    float*       __restrict__ agg)
{
    const int node = blockIdx.x * 4 + (threadIdx.x >> 6);
    const int co   = (threadIdx.x & 63) * 2;
    const int start = offsets[node];
    const int end   = offsets[node + 1];
    float ax = 0.f, ay = 0.f;
    int i = start;
    if (i < end && (i & 1)) {                   // align to int4
        const int2 es = sorted_es[i];
        const float2 ef = *(const float2*)(edge_feat + (size_t)es.x * H + co);
        const float2 nf = *(const float2*)(node_feat + (size_t)es.y * H + co);
        ax += ef.x + nf.x;  ay += ef.y + nf.y;
        ++i;
    }
    for (; i + 2 <= end; i += 2) {
        const int4 p = *(const int4*)&sorted_es[i];   // wave-uniform, 2 edges
        const float2 e0 = *(const float2*)(edge_feat + (size_t)p.x * H + co);
        const float2 n0 = *(const float2*)(node_feat + (size_t)p.y * H + co);
        const float2 e1 = *(const float2*)(edge_feat + (size_t)p.z * H + co);
        const float2 n1 = *(const float2*)(node_feat + (size_t)p.w * H + co);
        ax += e0.x + n0.x;  ay += e0.y + n0.y;
        ax += e1.x + n1.x;  ay += e1.y + n1.y;
    }
    if (i < end) {
        const int2 es = sorted_es[i];
        const float2 ef = *(const float2*)(edge_feat + (size_t)es.x * H + co);
        const float2 nf = *(const float2*)(node_feat + (size_t)es.y * H + co);
        ax += ef.x + nf.x;  ay += ef.y + nf.y;
    }
    float2* dst = (float2*)(agg + (size_t)node * H + co);
    dst->x = ax;
    dst->y = ay;
}

// ---------------------------------------------------------------------------
// Layer 1 GEMM: h = relu(agg @ w1 + b1).  [50000x128] @ [128x256].
// Block: 64 rows x 256 cols, 256 threads, thread tile 8x8.
// A from 32 KB LDS (wave-broadcast reads), W from global (L1/L2 resident).
// launch_bounds(256,2): allocator may use up to 256 VGPR -> no spill (~115).
// ---------------------------------------------------------------------------
__global__ __launch_bounds__(256, 2) void l1_kernel(
    const float* __restrict__ agg,
    const float* __restrict__ w1t, const float* __restrict__ b1,
    float* __restrict__ h)
{
    __shared__ float s_a[MT * H];               // 32 KB
    const int t = threadIdx.x;
    const long long nbase = (long long)blockIdx.x * MT;

    {   // stage 64 rows of agg (zero-pad past NN)
        const float4* src = (const float4*)(agg + nbase * H);
        const long long rem4 = ((long long)NN - nbase) * (H / 4);
        #pragma unroll
        for (int i = 0; i < 8; ++i) {
            const int idx = t + i * 256;        // 0..2047
            float4 v = make_float4(0.f, 0.f, 0.f, 0.f);
            if (idx < rem4) v = src[idx];
            *(float4*)&s_a[idx * 4] = v;
        }
    }
    __syncthreads();

    const int row0 = (t >> 5) * 8;              // 0..56
    const int col0 = (t & 31) * 8;              // 0..248
    float acc[8][8];
    #pragma unroll
    for (int j = 0; j < 8; ++j) {
        const float b = b1[col0 + j];
        #pragma unroll
        for (int i = 0; i < 8; ++i) acc[i][j] = b;
    }
    for (int k4 = 0; k4 < H / 4; ++k4) {
        float4 a[8];
        #pragma unroll
        for (int i = 0; i < 8; ++i)
            a[i] = *(const float4*)&s_a[(row0 + i) * H + k4 * 4];  // broadcast
        #pragma unroll
        for (int j = 0; j < 8; ++j) {
            const float4 w = *(const float4*)(w1t + (col0 + j) * H + k4 * 4);
            #pragma unroll
            for (int i = 0; i < 8; ++i) {
                acc[i][j] = fmaf(a[i].x, w.x, acc[i][j]);
                acc[i][j] = fmaf(a[i].y, w.y, acc[i][j]);
                acc[i][j] = fmaf(a[i].z, w.z, acc[i][j]);
                acc[i][j] = fmaf(a[i].w, w.w, acc[i][j]);
            }
        }
    }
    #pragma unroll
    for (int i = 0; i < 8; ++i) {
        const long long n = nbase + row0 + i;
        if (n < NN) {
            #pragma unroll
            for (int j4 = 0; j4 < 2; ++j4) {
                float4 v;
                v.x = fmaxf(acc[i][j4 * 4 + 0], 0.f);
                v.y = fmaxf(acc[i][j4 * 4 + 1], 0.f);
                v.z = fmaxf(acc[i][j4 * 4 + 2], 0.f);
                v.w = fmaxf(acc[i][j4 * 4 + 3], 0.f);
                *(float4*)(h + n * H2 + col0 + j4 * 4) = v;
            }
        }
    }
}

// ---------------------------------------------------------------------------
// Layer 2 GEMM: out = h @ w2 + b2.  [50000x256] @ [256x128].
// Block: 64 rows x 128 cols, 256 threads, thread tile 8x4.
// h-tile from 64 KB LDS, W from global (L1-resident; 32 B/cyc demand).
// ---------------------------------------------------------------------------
__global__ __launch_bounds__(256, 2) void l2_kernel(
    const float* __restrict__ h,
    const float* __restrict__ w2t, const float* __restrict__ b2,
    float* __restrict__ out)
{
    __shared__ float s_h[MT * H2];              // 64 KB
    const int t = threadIdx.x;
    const long long nbase = (long long)blockIdx.x * MT;

    {   // stage 64 rows of h (zero-pad past NN)
        const float4* src = (const float4*)(h + nbase * H2);
        const long long rem4 = ((long long)NN - nbase) * (H2 / 4);
        #pragma unroll
        for (int i = 0; i < 16; ++i) {
            const int idx = t + i * 256;        // 0..4095
            float4 v = make_float4(0.f, 0.f, 0.f, 0.f);
            if (idx < rem4) v = src[idx];
            *(float4*)&s_h[idx * 4] = v;
        }
    }
    __syncthreads();

    const int row0 = (t >> 5) * 8;              // 0..56
    const int col0 = (t & 31) * 4;              // 0..124
    float acc[8][4];
    #pragma unroll
    for (int j = 0; j < 4; ++j) {
        const float b = b2[col0 + j];
        #pragma unroll
        for (int i = 0; i < 8; ++i) acc[i][j] = b;
    }
    for (int k4 = 0; k4 < H2 / 4; ++k4) {
        float4 a[8];
        #pragma unroll
        for (int i = 0; i < 8; ++i)
            a[i] = *(const float4*)&s_h[(row0 + i) * H2 + k4 * 4];  // broadcast
        #pragma unroll
        for (int j = 0; j < 4; ++j) {
            const float4 w = *(const float4*)(w2t + (col0 + j) * H2 + k4 * 4);
            #pragma unroll
            for (int i = 0; i < 8; ++i) {
                acc[i][j] = fmaf(a[i].x, w.x, acc[i][j]);
                acc[i][j] = fmaf(a[i].y, w.y, acc[i][j]);
                acc[i][j] = fmaf(a[i].z, w.z, acc[i][j]);
                acc[i][j] = fmaf(a[i].w, w.w, acc[i][j]);
            }
        }
    }
    #pragma unroll
    for (int i = 0; i < 8; ++i) {
        const long long n = nbase + row0 + i;
        if (n < NN) {
            float4 v;
            v.x = acc[i][0]; v.y = acc[i][1]; v.z = acc[i][2]; v.w = acc[i][3];
            *(float4*)(out + n * H + col0) = v;
        }
    }
}

// ---------------------------------------------------------------------------
// Fallback path (tiny workspace): atomic scatter + simple MLP.
// ---------------------------------------------------------------------------
__global__ __launch_bounds__(256) void scatter_kernel(
    const float* __restrict__ node_feat,
    const float* __restrict__ edge_feat,
    const int*   __restrict__ edge_src,
    const int*   __restrict__ edge_dst,
    float*       __restrict__ agg)
{
    long long tid = (long long)blockIdx.x * blockDim.x + threadIdx.x;
    const long long total = (long long)NE * 32;
    if (tid >= total) return;
    int e = (int)(tid >> 5);
    int q = (int)((tid & 31) << 2);
    int s = edge_src[e];
    int d = edge_dst[e];
    const float4 nf = *(const float4*)(node_feat + (long long)s * H + q);
    const float4 ef = *(const float4*)(edge_feat + (long long)e * H + q);
    float* dst = agg + (long long)d * H + q;
    atomicAdd(dst + 0, nf.x + ef.x);
    atomicAdd(dst + 1, nf.y + ef.y);
    atomicAdd(dst + 2, nf.z + ef.z);
    atomicAdd(dst + 3, nf.w + ef.w);
}

__global__ __launch_bounds__(256) void mlp_simple_kernel(
    const float* __restrict__ agg,
    const float* __restrict__ w1, const float* __restrict__ b1,
    const float* __restrict__ w2, const float* __restrict__ b2,
    float*       __restrict__ out)
{
    constexpr int NPB = 16;
    __shared__ float s_in[NPB][H];
    __shared__ float s_h [NPB][H2];
    const int t = threadIdx.x;
    const long long base = (long long)blockIdx.x * NPB;
    {
        const float4* src = (const float4*)(agg + base * H);
        float4* dst = (float4*)(&s_in[0][0]);
        dst[t]       = src[t];
        dst[t + 256] = src[t + 256];
    }
    __syncthreads();
    float acc[NPB];
    {
        const float b = b1[t];
        #pragma unroll
        for (int n = 0; n < NPB; ++n) acc[n] = b;
    }
    #pragma unroll 4
    for (int k = 0; k < H; ++k) {
        const float w = w1[k * H2 + t];
        #pragma unroll
        for (int n = 0; n < NPB; ++n) acc[n] = fmaf(s_in[n][k], w, acc[n]);
    }
    #pragma unroll
    for (int n = 0; n < NPB; ++n) s_h[n][t] = fmaxf(acc[n], 0.0f);
    __syncthreads();
    const int j = t & (H - 1);
    const int g = t >> 7;
    float acc2[NPB / 2];
    {
        const float b = b2[j];
        #pragma unroll
        for (int n = 0; n < NPB / 2; ++n) acc2[n] = b;
    }
    #pragma unroll 4
    for (int k = 0; k < H2; ++k) {
        const float w = w2[k * H + j];
        #pragma unroll
        for (int n = 0; n < NPB / 2; ++n)
            acc2[n] = fmaf(s_h[g * (NPB / 2) + n][k], w, acc2[n]);
    }
    #pragma unroll
    for (int n = 0; n < NPB / 2; ++n)
        out[(base + g * (NPB / 2) + n) * H + j] = acc2[n];
}

__global__ __launch_bounds__(256) void zero_agg_kernel(float4* __restrict__ p, int n4)
{
    int i = blockIdx.x * blockDim.x + threadIdx.x;
    if (i < n4) p[i] = make_float4(0.f, 0.f, 0.f, 0.f);
}

// ---------------------------------------------------------------------------
extern "C" void kernel_launch(void* const* d_in, const int* in_sizes, int n_in,
                              void* d_out, int out_size, void* d_ws, size_t ws_size,
                              hipStream_t stream)
{
    const float* node_feat = (const float*)d_in[0];
    const float* edge_feat = (const float*)d_in[1];
    const int*   edge_src  = (const int*)  d_in[2];
    const int*   edge_dst  = (const int*)  d_in[3];
    const float* w1 = (const float*)d_in[4];
    const float* b1 = (const float*)d_in[5];
    const float* w2 = (const float*)d_in[6];
    const float* b2 = (const float*)d_in[7];
    float* out = (float*)d_out;

    // Workspace layout (256-B aligned regions)
    const size_t count_b  = ((size_t)NN * 4 + 255) & ~(size_t)255;        // 200 KB
    const size_t cursor_b = count_b;                                       // 200 KB
    const size_t offs_b   = (((size_t)NN + 1) * 4 + 255) & ~(size_t)255;   // 200 KB
    const size_t es_b     = ((size_t)NE * 8 + 255) & ~(size_t)255;         // 6.4 MB
    const size_t w1t_b    = (size_t)H * H2 * 4;                            // 128 KB
    const size_t w2t_b    = (size_t)H * H2 * 4;                            // 128 KB
    const size_t agg_b    = (size_t)NN * H * sizeof(float);                // 25.6 MB
    const size_t h_b      = (size_t)NN * H2 * sizeof(float);               // 51.2 MB
    const size_t need     = count_b + cursor_b + offs_b + es_b
                          + w1t_b + w2t_b + agg_b + h_b;                   // ~84 MB

    const int gemm_grid = (NN + MT - 1) / MT;   // 782

    if (ws_size >= need) {
        char* p = (char*)d_ws;
        int*   count     = (int*)p;              p += count_b;
        int*   cursor    = (int*)p;              p += cursor_b;
        int*   offsets   = (int*)p;              p += offs_b;
        int2*  sorted_es = (int2*)p;             p += es_b;
        float* w1t       = (float*)p;            p += w1t_b;
        float* w2t       = (float*)p;            p += w2t_b;
        float* agg       = (float*)p;            p += agg_b;
        float* h         = (float*)p;

        {
            const int n4 = (int)((count_b + cursor_b) / 16);
            zero_kernel<<<(n4 + 255) / 256, 256, 0, stream>>>((int4*)d_ws, n4);
        }

        const int eb = 256, eg = (NE + eb - 1) / eb;   // 3125
        count_kernel<<<eg, eb, 0, stream>>>(edge_dst, count);
        scan_kernel<<<1, 1024, 0, stream>>>(count, offsets);
        place_kernel<<<eg, eb, 0, stream>>>(edge_dst, edge_src, offsets, cursor, sorted_es);
        prep_kernel<<<(H * H2 + 255) / 256, 256, 0, stream>>>(w1, w2, w1t, w2t);
        gather_kernel<<<NN / 4, 256, 0, stream>>>(
            node_feat, edge_feat, sorted_es, offsets, agg);
        l1_kernel<<<gemm_grid, 256, 0, stream>>>(agg, w1t, b1, h);
        l2_kernel<<<gemm_grid, 256, 0, stream>>>(h, w2t, b2, out);
    } else {
        // Fallback: atomic path + simple MLP
        const size_t agg_bytes = (size_t)NN * H * sizeof(float);
        float* agg = (ws_size >= agg_bytes) ? (float*)d_ws : out;
        {
            const int n4 = (int)(agg_bytes / 16);
            zero_agg_kernel<<<(n4 + 255) / 256, 256, 0, stream>>>((float4*)agg, n4);
        }
        const long long total = (long long)NE * 32;
        const int block = 256;
        const int grid  = (int)((total + block - 1) / block);
        scatter_kernel<<<grid, block, 0, stream>>>(
            node_feat, edge_feat, edge_src, edge_dst, agg);
        mlp_simple_kernel<<<NN / 16, 256, 0, stream>>>(agg, w1, b1, w2, b2, out);
    }
}

// Round 7
// 493.652 us; speedup vs baseline: 1.3484x; 1.1042x over previous
//
#include <hip/hip_runtime.h>

// GIN fused: msg = node_feat[src] + edge_feat; agg = segment_sum(msg, dst);
// out = relu(agg@w1+b1)@w2+b2.  N=50000, E=800000, H=128.
//
// Round 7: GEMMs restructured for wave-uniform weight loads (lane=row,
// wave=col-slice; W read broadcast from original layout, A transposed in LDS,
// pad-130 conflict-free reads). Hierarchical 3-kernel scan. Gather unrolled
// to 4 edges in flight.

constexpr int NN = 50000;
constexpr int NE = 800000;
constexpr int H  = 128;   // hidden
constexpr int H2 = 256;   // 2*hidden
constexpr int RT = 128;   // rows per GEMM block tile
constexpr int SP = 130;   // LDS row-pad stride (even -> aligned b64, bank-spread)

// ---------------------------------------------------------------------------
__global__ __launch_bounds__(256) void zero_kernel(int4* __restrict__ p, int n4)
{
    int i = blockIdx.x * blockDim.x + threadIdx.x;
    if (i < n4) p[i] = make_int4(0, 0, 0, 0);
}

// ---------------------------------------------------------------------------
// CSR step 1: histogram of edge_dst
// ---------------------------------------------------------------------------
__global__ __launch_bounds__(256) void count_kernel(
    const int* __restrict__ edge_dst, int* __restrict__ count)
{
    int e = blockIdx.x * blockDim.x + threadIdx.x;
    if (e < NE) atomicAdd(&count[edge_dst[e]], 1);
}

// ---------------------------------------------------------------------------
// CSR step 2: hierarchical exclusive scan (3 tiny parallel kernels)
// ---------------------------------------------------------------------------
__global__ __launch_bounds__(256) void scan1_kernel(
    const int* __restrict__ count, int* __restrict__ bsum)
{
    __shared__ int red[256];
    const int t = threadIdx.x;
    const int i = blockIdx.x * 256 + t;
    red[t] = (i < NN) ? count[i] : 0;
    __syncthreads();
    for (int s = 128; s > 0; s >>= 1) {
        if (t < s) red[t] += red[t + s];
        __syncthreads();
    }
    if (t == 0) bsum[blockIdx.x] = red[0];
}

__global__ __launch_bounds__(256) void scan2_kernel(
    const int* __restrict__ bsum, int* __restrict__ bexc, int nb)
{
    __shared__ int s[256];
    const int t = threadIdx.x;
    s[t] = (t < nb) ? bsum[t] : 0;
    __syncthreads();
    for (int off = 1; off < 256; off <<= 1) {
        int v = (t >= off) ? s[t - off] : 0;
        __syncthreads();
        s[t] += v;
        __syncthreads();
    }
    if (t < nb) bexc[t] = (t == 0) ? 0 : s[t - 1];
}

__global__ __launch_bounds__(256) void scan3_kernel(
    const int* __restrict__ count, const int* __restrict__ bexc,
    int* __restrict__ offsets)
{
    __shared__ int s[256];
    const int t = threadIdx.x;
    const int i = blockIdx.x * 256 + t;
    const int c = (i < NN) ? count[i] : 0;
    s[t] = c;
    __syncthreads();
    for (int off = 1; off < 256; off <<= 1) {
        int v = (t >= off) ? s[t - off] : 0;
        __syncthreads();
        s[t] += v;
        __syncthreads();
    }
    if (i < NN) {
        const int excl = bexc[blockIdx.x] + s[t] - c;
        offsets[i] = excl;
        if (i == NN - 1) offsets[NN] = excl + c;
    }
}

// ---------------------------------------------------------------------------
// CSR step 3: place (eid, src) pairs grouped by destination
// ---------------------------------------------------------------------------
__global__ __launch_bounds__(256) void place_kernel(
    const int* __restrict__ edge_dst, const int* __restrict__ edge_src,
    const int* __restrict__ offsets,
    int* __restrict__ cursor, int2* __restrict__ sorted_es)
{
    int e = blockIdx.x * blockDim.x + threadIdx.x;
    if (e < NE) {
        int d = edge_dst[e];
        int pos = offsets[d] + atomicAdd(&cursor[d], 1);
        sorted_es[pos] = make_int2(e, edge_src[e]);
    }
}

// ---------------------------------------------------------------------------
// Gather: one 64-lane wave per node, float2 per lane, wave-uniform es loads,
// 4 edges (8 feature loads) in flight per iteration.
// ---------------------------------------------------------------------------
__global__ __launch_bounds__(256) void gather_kernel(
    const float* __restrict__ node_feat,
    const float* __restrict__ edge_feat,
    const int2*  __restrict__ sorted_es,
    const int*   __restrict__ offsets,
    float*       __restrict__ agg)
{
    const int node = blockIdx.x * 4 + (threadIdx.x >> 6);
    const int co   = (threadIdx.x & 63) * 2;
    const int start = offsets[node];
    const int end   = offsets[node + 1];
    float ax = 0.f, ay = 0.f;
    int i = start;
    if ((i & 1) && i < end) {                   // align to int4
        const int2 es = sorted_es[i];
        const float2 ef = *(const float2*)(edge_feat + (size_t)es.x * H + co);
        const float2 nf = *(const float2*)(node_feat + (size_t)es.y * H + co);
        ax += ef.x + nf.x;  ay += ef.y + nf.y;
        ++i;
    }
    for (; i + 4 <= end; i += 4) {
        const int4 p0 = *(const int4*)&sorted_es[i];
        const int4 p1 = *(const int4*)&sorted_es[i + 2];
        const float2 e0 = *(const float2*)(edge_feat + (size_t)p0.x * H + co);
        const float2 n0 = *(const float2*)(node_feat + (size_t)p0.y * H + co);
        const float2 e1 = *(const float2*)(edge_feat + (size_t)p0.z * H + co);
        const float2 n1 = *(const float2*)(node_feat + (size_t)p0.w * H + co);
        const float2 e2 = *(const float2*)(edge_feat + (size_t)p1.x * H + co);
        const float2 n2 = *(const float2*)(node_feat + (size_t)p1.y * H + co);
        const float2 e3 = *(const float2*)(edge_feat + (size_t)p1.z * H + co);
        const float2 n3 = *(const float2*)(node_feat + (size_t)p1.w * H + co);
        ax += e0.x + n0.x;  ay += e0.y + n0.y;
        ax += e1.x + n1.x;  ay += e1.y + n1.y;
        ax += e2.x + n2.x;  ay += e2.y + n2.y;
        ax += e3.x + n3.x;  ay += e3.y + n3.y;
    }
    for (; i + 2 <= end; i += 2) {
        const int4 p = *(const int4*)&sorted_es[i];
        const float2 e0 = *(const float2*)(edge_feat + (size_t)p.x * H + co);
        const float2 n0 = *(const float2*)(node_feat + (size_t)p.y * H + co);
        const float2 e1 = *(const float2*)(edge_feat + (size_t)p.z * H + co);
        const float2 n1 = *(const float2*)(node_feat + (size_t)p.w * H + co);
        ax += e0.x + n0.x;  ay += e0.y + n0.y;
        ax += e1.x + n1.x;  ay += e1.y + n1.y;
    }
    if (i < end) {
        const int2 es = sorted_es[i];
        const float2 ef = *(const float2*)(edge_feat + (size_t)es.x * H + co);
        const float2 nf = *(const float2*)(node_feat + (size_t)es.y * H + co);
        ax += ef.x + nf.x;  ay += ef.y + nf.y;
    }
    float2* dst = (float2*)(agg + (size_t)node * H + co);
    dst->x = ax;
    dst->y = ay;
}

// ---------------------------------------------------------------------------
// Layer 1 GEMM: h = relu(agg @ w1 + b1).  [N x 128] @ [128 x 256].
// Block: 128 rows x 256 cols, 256 threads (4 waves).
// Wave w -> cols [w*64, w*64+64); lane l -> rows 2l, 2l+1.
// A transposed in LDS s_aT[k][row] (pad SP=130): compute read = conflict-free
// ds_read_b64. W loads are WAVE-UNIFORM float4 from the ORIGINAL w1 layout
// (w1[k*256+col], col wave-invariant) -> 1 L1 line per instruction.
// acc[2][64] = 128 VGPR; launch_bounds(256,2) -> no spill, 2 blocks/CU.
// ---------------------------------------------------------------------------
__global__ __launch_bounds__(256, 2) void l1_kernel(
    const float* __restrict__ agg,
    const float* __restrict__ w1, const float* __restrict__ b1,
    float* __restrict__ h)
{
    __shared__ float s_aT[H * SP];              // 128 k x 130 = 66.6 KB
    const int t = threadIdx.x;
    const long long nbase = (long long)blockIdx.x * RT;
    const int rem = (int)(NN - nbase < RT ? NN - nbase : RT);

    // stage transposed: lanes read 512B-contiguous rows, scatter to s_aT
    #pragma unroll
    for (int it = 0; it < 16; ++it) {
        const int idx = t + it * 256;           // 0..4095
        const int row = idx >> 5;               // 0..127
        const int k4  = idx & 31;               // 0..31
        float4 v = make_float4(0.f, 0.f, 0.f, 0.f);
        if (row < rem) v = *(const float4*)(agg + (nbase + row) * H + k4 * 4);
        s_aT[(k4 * 4 + 0) * SP + row] = v.x;
        s_aT[(k4 * 4 + 1) * SP + row] = v.y;
        s_aT[(k4 * 4 + 2) * SP + row] = v.z;
        s_aT[(k4 * 4 + 3) * SP + row] = v.w;
    }
    __syncthreads();

    const int wc0 = (t >> 6) * 64;              // wave col base (uniform)
    const int r0  = (t & 63) * 2;               // lane rows r0, r0+1

    float acc[2][64];
    #pragma unroll
    for (int j4 = 0; j4 < 16; ++j4) {
        const float4 b = *(const float4*)(b1 + wc0 + j4 * 4);
        acc[0][j4 * 4 + 0] = b.x;  acc[1][j4 * 4 + 0] = b.x;
        acc[0][j4 * 4 + 1] = b.y;  acc[1][j4 * 4 + 1] = b.y;
        acc[0][j4 * 4 + 2] = b.z;  acc[1][j4 * 4 + 2] = b.z;
        acc[0][j4 * 4 + 3] = b.w;  acc[1][j4 * 4 + 3] = b.w;
    }

    #pragma unroll 2
    for (int k = 0; k < H; ++k) {
        const float2 a = *(const float2*)&s_aT[k * SP + r0];
        const float* wrow = w1 + k * H2 + wc0;
        #pragma unroll
        for (int j4 = 0; j4 < 16; ++j4) {
            const float4 w = *(const float4*)(wrow + j4 * 4);   // wave-uniform
            acc[0][j4 * 4 + 0] = fmaf(a.x, w.x, acc[0][j4 * 4 + 0]);
            acc[1][j4 * 4 + 0] = fmaf(a.y, w.x, acc[1][j4 * 4 + 0]);
            acc[0][j4 * 4 + 1] = fmaf(a.x, w.y, acc[0][j4 * 4 + 1]);
            acc[1][j4 * 4 + 1] = fmaf(a.y, w.y, acc[1][j4 * 4 + 1]);
            acc[0][j4 * 4 + 2] = fmaf(a.x, w.z, acc[0][j4 * 4 + 2]);
            acc[1][j4 * 4 + 2] = fmaf(a.y, w.z, acc[1][j4 * 4 + 2]);
            acc[0][j4 * 4 + 3] = fmaf(a.x, w.w, acc[0][j4 * 4 + 3]);
            acc[1][j4 * 4 + 3] = fmaf(a.y, w.w, acc[1][j4 * 4 + 3]);
        }
    }

    #pragma unroll
    for (int i = 0; i < 2; ++i) {
        const long long n = nbase + r0 + i;
        if (n < NN) {
            float* hrow = h + n * H2 + wc0;
            #pragma unroll
            for (int j4 = 0; j4 < 16; ++j4) {
                float4 v;
                v.x = fmaxf(acc[i][j4 * 4 + 0], 0.f);
                v.y = fmaxf(acc[i][j4 * 4 + 1], 0.f);
                v.z = fmaxf(acc[i][j4 * 4 + 2], 0.f);
                v.w = fmaxf(acc[i][j4 * 4 + 3], 0.f);
                *(float4*)(hrow + j4 * 4) = v;
            }
        }
    }
}

// ---------------------------------------------------------------------------
// Layer 2 GEMM: out = h @ w2 + b2.  [N x 256] @ [256 x 128].
// Block: 128 rows x 128 cols; wave w -> cols [w*32,+32); lane -> rows 2l,2l+1.
// K=256 in two 128-chunks staged transposed in LDS. W wave-uniform from w2.
// ---------------------------------------------------------------------------
__global__ __launch_bounds__(256, 2) void l2_kernel(
    const float* __restrict__ h,
    const float* __restrict__ w2, const float* __restrict__ b2,
    float* __restrict__ out)
{
    __shared__ float s_hT[128 * SP];            // 66.6 KB
    const int t = threadIdx.x;
    const long long nbase = (long long)blockIdx.x * RT;
    const int rem = (int)(NN - nbase < RT ? NN - nbase : RT);

    const int wc0 = (t >> 6) * 32;              // wave col base (uniform)
    const int r0  = (t & 63) * 2;

    float acc[2][32];
    #pragma unroll
    for (int j4 = 0; j4 < 8; ++j4) {
        const float4 b = *(const float4*)(b2 + wc0 + j4 * 4);
        acc[0][j4 * 4 + 0] = b.x;  acc[1][j4 * 4 + 0] = b.x;
        acc[0][j4 * 4 + 1] = b.y;  acc[1][j4 * 4 + 1] = b.y;
        acc[0][j4 * 4 + 2] = b.z;  acc[1][j4 * 4 + 2] = b.z;
        acc[0][j4 * 4 + 3] = b.w;  acc[1][j4 * 4 + 3] = b.w;
    }

    for (int cc = 0; cc < 2; ++cc) {
        if (cc) __syncthreads();                // prev chunk fully consumed
        #pragma unroll
        for (int it = 0; it < 16; ++it) {
            const int idx = t + it * 256;       // 0..4095
            const int row = idx >> 5;           // 0..127
            const int k4  = idx & 31;           // 0..31
            float4 v = make_float4(0.f, 0.f, 0.f, 0.f);
            if (row < rem)
                v = *(const float4*)(h + (nbase + row) * H2 + cc * 128 + k4 * 4);
            s_hT[(k4 * 4 + 0) * SP + row] = v.x;
            s_hT[(k4 * 4 + 1) * SP + row] = v.y;
            s_hT[(k4 * 4 + 2) * SP + row] = v.z;
            s_hT[(k4 * 4 + 3) * SP + row] = v.w;
        }
        __syncthreads();

        const float* wbase = w2 + (size_t)cc * 128 * H;
        #pragma unroll 2
        for (int k = 0; k < 128; ++k) {
            const float2 a = *(const float2*)&s_hT[k * SP + r0];
            const float* wrow = wbase + k * H + wc0;
            #pragma unroll
            for (int j4 = 0; j4 < 8; ++j4) {
                const float4 w = *(const float4*)(wrow + j4 * 4);  // uniform
                acc[0][j4 * 4 + 0] = fmaf(a.x, w.x, acc[0][j4 * 4 + 0]);
                acc[1][j4 * 4 + 0] = fmaf(a.y, w.x, acc[1][j4 * 4 + 0]);
                acc[0][j4 * 4 + 1] = fmaf(a.x, w.y, acc[0][j4 * 4 + 1]);
                acc[1][j4 * 4 + 1] = fmaf(a.y, w.y, acc[1][j4 * 4 + 1]);
                acc[0][j4 * 4 + 2] = fmaf(a.x, w.z, acc[0][j4 * 4 + 2]);
                acc[1][j4 * 4 + 2] = fmaf(a.y, w.z, acc[1][j4 * 4 + 2]);
                acc[0][j4 * 4 + 3] = fmaf(a.x, w.w, acc[0][j4 * 4 + 3]);
                acc[1][j4 * 4 + 3] = fmaf(a.y, w.w, acc[1][j4 * 4 + 3]);
            }
        }
    }

    #pragma unroll
    for (int i = 0; i < 2; ++i) {
        const long long n = nbase + r0 + i;
        if (n < NN) {
            float* orow = out + n * H + wc0;
            #pragma unroll
            for (int j4 = 0; j4 < 8; ++j4) {
                float4 v;
                v.x = acc[i][j4 * 4 + 0];
                v.y = acc[i][j4 * 4 + 1];
                v.z = acc[i][j4 * 4 + 2];
                v.w = acc[i][j4 * 4 + 3];
                *(float4*)(orow + j4 * 4) = v;
            }
        }
    }
}

// ---------------------------------------------------------------------------
// Fallback path (tiny workspace): atomic scatter + simple MLP.
// ---------------------------------------------------------------------------
__global__ __launch_bounds__(256) void scatter_kernel(
    const float* __restrict__ node_feat,
    const float* __restrict__ edge_feat,
    const int*   __restrict__ edge_src,
    const int*   __restrict__ edge_dst,
    float*       __restrict__ agg)
{
    long long tid = (long long)blockIdx.x * blockDim.x + threadIdx.x;
    const long long total = (long long)NE * 32;
    if (tid >= total) return;
    int e = (int)(tid >> 5);
    int q = (int)((tid & 31) << 2);
    int s = edge_src[e];
    int d = edge_dst[e];
    const float4 nf = *(const float4*)(node_feat + (long long)s * H + q);
    const float4 ef = *(const float4*)(edge_feat + (long long)e * H + q);
    float* dst = agg + (long long)d * H + q;
    atomicAdd(dst + 0, nf.x + ef.x);
    atomicAdd(dst + 1, nf.y + ef.y);
    atomicAdd(dst + 2, nf.z + ef.z);
    atomicAdd(dst + 3, nf.w + ef.w);
}

__global__ __launch_bounds__(256) void mlp_simple_kernel(
    const float* __restrict__ agg,
    const float* __restrict__ w1, const float* __restrict__ b1,
    const float* __restrict__ w2, const float* __restrict__ b2,
    float*       __restrict__ out)
{
    constexpr int NPB = 16;
    __shared__ float s_in[NPB][H];
    __shared__ float s_h [NPB][H2];
    const int t = threadIdx.x;
    const long long base = (long long)blockIdx.x * NPB;
    {
        const float4* src = (const float4*)(agg + base * H);
        float4* dst = (float4*)(&s_in[0][0]);
        dst[t]       = src[t];
        dst[t + 256] = src[t + 256];
    }
    __syncthreads();
    float acc[NPB];
    {
        const float b = b1[t];
        #pragma unroll
        for (int n = 0; n < NPB; ++n) acc[n] = b;
    }
    #pragma unroll 4
    for (int k = 0; k < H; ++k) {
        const float w = w1[k * H2 + t];
        #pragma unroll
        for (int n = 0; n < NPB; ++n) acc[n] = fmaf(s_in[n][k], w, acc[n]);
    }
    #pragma unroll
    for (int n = 0; n < NPB; ++n) s_h[n][t] = fmaxf(acc[n], 0.0f);
    __syncthreads();
    const int j = t & (H - 1);
    const int g = t >> 7;
    float acc2[NPB / 2];
    {
        const float b = b2[j];
        #pragma unroll
        for (int n = 0; n < NPB / 2; ++n) acc2[n] = b;
    }
    #pragma unroll 4
    for (int k = 0; k < H2; ++k) {
        const float w = w2[k * H + j];
        #pragma unroll
        for (int n = 0; n < NPB / 2; ++n)
            acc2[n] = fmaf(s_h[g * (NPB / 2) + n][k], w, acc2[n]);
    }
    #pragma unroll
    for (int n = 0; n < NPB / 2; ++n)
        out[(base + g * (NPB / 2) + n) * H + j] = acc2[n];
}

__global__ __launch_bounds__(256) void zero_agg_kernel(float4* __restrict__ p, int n4)
{
    int i = blockIdx.x * blockDim.x + threadIdx.x;
    if (i < n4) p[i] = make_float4(0.f, 0.f, 0.f, 0.f);
}

// ---------------------------------------------------------------------------
extern "C" void kernel_launch(void* const* d_in, const int* in_sizes, int n_in,
                              void* d_out, int out_size, void* d_ws, size_t ws_size,
                              hipStream_t stream)
{
    const float* node_feat = (const float*)d_in[0];
    const float* edge_feat = (const float*)d_in[1];
    const int*   edge_src  = (const int*)  d_in[2];
    const int*   edge_dst  = (const int*)  d_in[3];
    const float* w1 = (const float*)d_in[4];
    const float* b1 = (const float*)d_in[5];
    const float* w2 = (const float*)d_in[6];
    const float* b2 = (const float*)d_in[7];
    float* out = (float*)d_out;

    const int NB = (NN + 255) / 256;            // 196 scan blocks

    // Workspace layout (256-B aligned regions)
    const size_t count_b  = ((size_t)NN * 4 + 255) & ~(size_t)255;        // 200 KB
    const size_t cursor_b = count_b;                                       // 200 KB
    const size_t offs_b   = (((size_t)NN + 1) * 4 + 255) & ~(size_t)255;   // 200 KB
    const size_t bsum_b   = ((size_t)NB * 4 + 255) & ~(size_t)255;         // 1 KB
    const size_t bexc_b   = bsum_b;                                        // 1 KB
    const size_t es_b     = ((size_t)NE * 8 + 255) & ~(size_t)255;         // 6.4 MB
    const size_t agg_b    = (size_t)NN * H * sizeof(float);                // 25.6 MB
    const size_t h_b      = (size_t)NN * H2 * sizeof(float);               // 51.2 MB
    const size_t need     = count_b + cursor_b + offs_b + bsum_b + bexc_b
                          + es_b + agg_b + h_b;                            // ~84 MB

    if (ws_size >= need) {
        char* p = (char*)d_ws;
        int*   count     = (int*)p;              p += count_b;
        int*   cursor    = (int*)p;              p += cursor_b;
        int*   offsets   = (int*)p;              p += offs_b;
        int*   bsum      = (int*)p;              p += bsum_b;
        int*   bexc      = (int*)p;              p += bexc_b;
        int2*  sorted_es = (int2*)p;             p += es_b;
        float* agg       = (float*)p;            p += agg_b;
        float* h         = (float*)p;

        {
            const int n4 = (int)((count_b + cursor_b) / 16);
            zero_kernel<<<(n4 + 255) / 256, 256, 0, stream>>>((int4*)d_ws, n4);
        }

        const int eb = 256, eg = (NE + eb - 1) / eb;   // 3125
        count_kernel<<<eg, eb, 0, stream>>>(edge_dst, count);
        scan1_kernel<<<NB, 256, 0, stream>>>(count, bsum);
        scan2_kernel<<<1, 256, 0, stream>>>(bsum, bexc, NB);
        scan3_kernel<<<NB, 256, 0, stream>>>(count, bexc, offsets);
        place_kernel<<<eg, eb, 0, stream>>>(edge_dst, edge_src, offsets, cursor, sorted_es);
        gather_kernel<<<NN / 4, 256, 0, stream>>>(
            node_feat, edge_feat, sorted_es, offsets, agg);
        const int gemm_grid = (NN + RT - 1) / RT;      // 391
        l1_kernel<<<gemm_grid, 256, 0, stream>>>(agg, w1, b1, h);
        l2_kernel<<<gemm_grid, 256, 0, stream>>>(h, w2, b2, out);
    } else {
        // Fallback: atomic path + simple MLP
        const size_t agg_bytes = (size_t)NN * H * sizeof(float);
        float* agg = (ws_size >= agg_bytes) ? (float*)d_ws : out;
        {
            const int n4 = (int)(agg_bytes / 16);
            zero_agg_kernel<<<(n4 + 255) / 256, 256, 0, stream>>>((float4*)agg, n4);
        }
        const long long total = (long long)NE * 32;
        const int block = 256;
        const int grid  = (int)((total + block - 1) / block);
        scatter_kernel<<<grid, block, 0, stream>>>(
            node_feat, edge_feat, edge_src, edge_dst, agg);
        mlp_simple_kernel<<<NN / 16, 256, 0, stream>>>(agg, w1, b1, w2, b2, out);
    }
}

// Round 8
// 259.961 us; speedup vs baseline: 2.5606x; 1.8989x over previous
//
#include <hip/hip_runtime.h>

// GIN fused: msg = node_feat[src] + edge_feat; agg = segment_sum(msg, dst);
// out = relu(agg@w1+b1)@w2+b2.  N=50000, E=800000, H=128.
//
// Round 8: GEMMs moved to bf16 MFMA (16x16x32). Threshold is bf16-floor
// (0.5375); math becomes ~3us, GEMMs now memory-bound (~65MB total).
// Gather stores agg as bf16 (half traffic). CSR build unchanged (round 7).

constexpr int NN = 50000;
constexpr int NE = 800000;
constexpr int H  = 128;   // hidden
constexpr int H2 = 256;   // 2*hidden

typedef short short8_t __attribute__((ext_vector_type(8)));
typedef float f32x4    __attribute__((ext_vector_type(4)));

__device__ inline short f2bf(float f) {
    union { float f; unsigned u; } c; c.f = f;
    unsigned r = c.u + 0x7FFF + ((c.u >> 16) & 1);   // RTNE
    return (short)(r >> 16);
}

// ---------------------------------------------------------------------------
__global__ __launch_bounds__(256) void zero_kernel(int4* __restrict__ p, int n4)
{
    int i = blockIdx.x * blockDim.x + threadIdx.x;
    if (i < n4) p[i] = make_int4(0, 0, 0, 0);
}

// ---------------------------------------------------------------------------
// CSR step 1: histogram of edge_dst
// ---------------------------------------------------------------------------
__global__ __launch_bounds__(256) void count_kernel(
    const int* __restrict__ edge_dst, int* __restrict__ count)
{
    int e = blockIdx.x * blockDim.x + threadIdx.x;
    if (e < NE) atomicAdd(&count[edge_dst[e]], 1);
}

// ---------------------------------------------------------------------------
// CSR step 2: hierarchical exclusive scan
// ---------------------------------------------------------------------------
__global__ __launch_bounds__(256) void scan1_kernel(
    const int* __restrict__ count, int* __restrict__ bsum)
{
    __shared__ int red[256];
    const int t = threadIdx.x;
    const int i = blockIdx.x * 256 + t;
    red[t] = (i < NN) ? count[i] : 0;
    __syncthreads();
    for (int s = 128; s > 0; s >>= 1) {
        if (t < s) red[t] += red[t + s];
        __syncthreads();
    }
    if (t == 0) bsum[blockIdx.x] = red[0];
}

__global__ __launch_bounds__(256) void scan2_kernel(
    const int* __restrict__ bsum, int* __restrict__ bexc, int nb)
{
    __shared__ int s[256];
    const int t = threadIdx.x;
    s[t] = (t < nb) ? bsum[t] : 0;
    __syncthreads();
    for (int off = 1; off < 256; off <<= 1) {
        int v = (t >= off) ? s[t - off] : 0;
        __syncthreads();
        s[t] += v;
        __syncthreads();
    }
    if (t < nb) bexc[t] = (t == 0) ? 0 : s[t - 1];
}

__global__ __launch_bounds__(256) void scan3_kernel(
    const int* __restrict__ count, const int* __restrict__ bexc,
    int* __restrict__ offsets)
{
    __shared__ int s[256];
    const int t = threadIdx.x;
    const int i = blockIdx.x * 256 + t;
    const int c = (i < NN) ? count[i] : 0;
    s[t] = c;
    __syncthreads();
    for (int off = 1; off < 256; off <<= 1) {
        int v = (t >= off) ? s[t - off] : 0;
        __syncthreads();
        s[t] += v;
        __syncthreads();
    }
    if (i < NN) {
        const int excl = bexc[blockIdx.x] + s[t] - c;
        offsets[i] = excl;
        if (i == NN - 1) offsets[NN] = excl + c;
    }
}

// ---------------------------------------------------------------------------
// CSR step 3: place (eid, src) pairs grouped by destination
// ---------------------------------------------------------------------------
__global__ __launch_bounds__(256) void place_kernel(
    const int* __restrict__ edge_dst, const int* __restrict__ edge_src,
    const int* __restrict__ offsets,
    int* __restrict__ cursor, int2* __restrict__ sorted_es)
{
    int e = blockIdx.x * blockDim.x + threadIdx.x;
    if (e < NE) {
        int d = edge_dst[e];
        int pos = offsets[d] + atomicAdd(&cursor[d], 1);
        sorted_es[pos] = make_int2(e, edge_src[e]);
    }
}

// ---------------------------------------------------------------------------
// Weight pack: MFMA B-fragment layout, bf16.
// w1p[((kk*16+ct)*64+l)*8+j] = bf16(w1[(kk*32+(l>>4)*8+j)*256 + ct*16+(l&15)])
// w2p[((kk*8 +ct)*64+l)*8+j] = bf16(w2[(kk*32+(l>>4)*8+j)*128 + ct*16+(l&15)])
// ---------------------------------------------------------------------------
__global__ __launch_bounds__(256) void pack_kernel(
    const float* __restrict__ w1, const float* __restrict__ w2,
    short* __restrict__ w1p, short* __restrict__ w2p)
{
    int i = blockIdx.x * 256 + threadIdx.x;   // 0..32767
    if (i < 32768) {
        {
            int j = i & 7, l = (i >> 3) & 63, ct = (i >> 9) & 15, kk = i >> 13;
            w1p[i] = f2bf(w1[(kk * 32 + (l >> 4) * 8 + j) * H2 + ct * 16 + (l & 15)]);
        }
        {
            int j = i & 7, l = (i >> 3) & 63, ct = (i >> 9) & 7, kk = i >> 12;
            w2p[i] = f2bf(w2[(kk * 32 + (l >> 4) * 8 + j) * H + ct * 16 + (l & 15)]);
        }
    }
}

// ---------------------------------------------------------------------------
// Gather: one 64-lane wave per node, float2 (fp32) accumulate, bf16 store.
// Wave-uniform es loads, 4 edges (8 feature loads) in flight per iteration.
// ---------------------------------------------------------------------------
__global__ __launch_bounds__(256) void gather_kernel(
    const float* __restrict__ node_feat,
    const float* __restrict__ edge_feat,
    const int2*  __restrict__ sorted_es,
    const int*   __restrict__ offsets,
    short*       __restrict__ aggb)
{
    const int node = blockIdx.x * 4 + (threadIdx.x >> 6);
    const int co   = (threadIdx.x & 63) * 2;
    const int start = offsets[node];
    const int end   = offsets[node + 1];
    float ax = 0.f, ay = 0.f;
    int i = start;
    if ((i & 1) && i < end) {
        const int2 es = sorted_es[i];
        const float2 ef = *(const float2*)(edge_feat + (size_t)es.x * H + co);
        const float2 nf = *(const float2*)(node_feat + (size_t)es.y * H + co);
        ax += ef.x + nf.x;  ay += ef.y + nf.y;
        ++i;
    }
    for (; i + 4 <= end; i += 4) {
        const int4 p0 = *(const int4*)&sorted_es[i];
        const int4 p1 = *(const int4*)&sorted_es[i + 2];
        const float2 e0 = *(const float2*)(edge_feat + (size_t)p0.x * H + co);
        const float2 n0 = *(const float2*)(node_feat + (size_t)p0.y * H + co);
        const float2 e1 = *(const float2*)(edge_feat + (size_t)p0.z * H + co);
        const float2 n1 = *(const float2*)(node_feat + (size_t)p0.w * H + co);
        const float2 e2 = *(const float2*)(edge_feat + (size_t)p1.x * H + co);
        const float2 n2 = *(const float2*)(node_feat + (size_t)p1.y * H + co);
        const float2 e3 = *(const float2*)(edge_feat + (size_t)p1.z * H + co);
        const float2 n3 = *(const float2*)(node_feat + (size_t)p1.w * H + co);
        ax += e0.x + n0.x;  ay += e0.y + n0.y;
        ax += e1.x + n1.x;  ay += e1.y + n1.y;
        ax += e2.x + n2.x;  ay += e2.y + n2.y;
        ax += e3.x + n3.x;  ay += e3.y + n3.y;
    }
    for (; i + 2 <= end; i += 2) {
        const int4 p = *(const int4*)&sorted_es[i];
        const float2 e0 = *(const float2*)(edge_feat + (size_t)p.x * H + co);
        const float2 n0 = *(const float2*)(node_feat + (size_t)p.y * H + co);
        const float2 e1 = *(const float2*)(edge_feat + (size_t)p.z * H + co);
        const float2 n1 = *(const float2*)(node_feat + (size_t)p.w * H + co);
        ax += e0.x + n0.x;  ay += e0.y + n0.y;
        ax += e1.x + n1.x;  ay += e1.y + n1.y;
    }
    if (i < end) {
        const int2 es = sorted_es[i];
        const float2 ef = *(const float2*)(edge_feat + (size_t)es.x * H + co);
        const float2 nf = *(const float2*)(node_feat + (size_t)es.y * H + co);
        ax += ef.x + nf.x;  ay += ef.y + nf.y;
    }
    const unsigned pk = (unsigned)(unsigned short)f2bf(ax)
                      | ((unsigned)(unsigned short)f2bf(ay) << 16);
    *(unsigned*)(aggb + (size_t)node * H + co) = pk;
}

// ---------------------------------------------------------------------------
// Layer 1: h = relu(agg @ w1 + b1), bf16 MFMA 16x16x32.
// Block = 4 waves x 16 rows = 64 rows; each wave does all 256 cols (16 tiles).
// A-frag: lane l -> A[row=l&15][k=(l>>4)*8+j] straight from bf16 agg rows.
// B-frag: packed w1p (b128/lane, coalesced, L1-resident).
// D: col=lane&15, row=(lane>>4)*4+reg (m89-verified) -> LDS -> coalesced store.
// ---------------------------------------------------------------------------
__global__ __launch_bounds__(256) void l1_kernel(
    const short* __restrict__ aggb, const short* __restrict__ w1p,
    const float* __restrict__ b1, short* __restrict__ hb)
{
    __shared__ short s_c[4][16][H2];            // 32 KB
    const int t = threadIdx.x;
    const int wid = t >> 6, l = t & 63;
    const int lrow = l & 15, lk = l >> 4;
    const long long mrow = (long long)blockIdx.x * 64 + wid * 16;

    f32x4 acc[16];
    #pragma unroll
    for (int ct = 0; ct < 16; ++ct) acc[ct] = (f32x4){0.f, 0.f, 0.f, 0.f};

    const short8_t* bfr = (const short8_t*)w1p;
    #pragma unroll
    for (int kk = 0; kk < 4; ++kk) {
        short8_t a = {0, 0, 0, 0, 0, 0, 0, 0};
        const long long ar = mrow + lrow;
        if (ar < NN)
            a = *(const short8_t*)(aggb + ar * H + kk * 32 + lk * 8);
        #pragma unroll
        for (int ct = 0; ct < 16; ++ct) {
            const short8_t b = bfr[(kk * 16 + ct) * 64 + l];
            acc[ct] = __builtin_amdgcn_mfma_f32_16x16x32_bf16(a, b, acc[ct], 0, 0, 0);
        }
    }

    // epilogue: bias + relu -> bf16 -> LDS (own wave region)
    #pragma unroll
    for (int ct = 0; ct < 16; ++ct) {
        const float b = b1[ct * 16 + lrow];
        #pragma unroll
        for (int r = 0; r < 4; ++r)
            s_c[wid][lk * 4 + r][ct * 16 + lrow] = f2bf(acc[ct][r] + b > 0.f ? acc[ct][r] + b : 0.f);
    }
    __syncthreads();

    // coalesced store: wave region = 16 rows x 512 B contiguous
    const short* reg = &s_c[wid][0][0];
    #pragma unroll
    for (int it = 0; it < 8; ++it) {
        const int off = it * 64 + l;            // 16B units, 0..511
        const long long row = mrow + (off >> 5);
        if (row < NN) {
            const short8_t v = ((const short8_t*)reg)[off];
            *(short8_t*)(hb + row * H2 + (off & 31) * 8) = v;
        }
    }
}

// ---------------------------------------------------------------------------
// Layer 2: out = h @ w2 + b2, bf16 MFMA, fp32 out.
// Same structure; K=256 (8 k-tiles), N=128 (8 col-tiles).
// ---------------------------------------------------------------------------
__global__ __launch_bounds__(256) void l2_kernel(
    const short* __restrict__ hb, const short* __restrict__ w2p,
    const float* __restrict__ b2, float* __restrict__ out)
{
    __shared__ float s_c[4][16][H];             // 32 KB
    const int t = threadIdx.x;
    const int wid = t >> 6, l = t & 63;
    const int lrow = l & 15, lk = l >> 4;
    const long long mrow = (long long)blockIdx.x * 64 + wid * 16;

    f32x4 acc[8];
    #pragma unroll
    for (int ct = 0; ct < 8; ++ct) acc[ct] = (f32x4){0.f, 0.f, 0.f, 0.f};

    const short8_t* bfr = (const short8_t*)w2p;
    #pragma unroll
    for (int kk = 0; kk < 8; ++kk) {
        short8_t a = {0, 0, 0, 0, 0, 0, 0, 0};
        const long long ar = mrow + lrow;
        if (ar < NN)
            a = *(const short8_t*)(hb + ar * H2 + kk * 32 + lk * 8);
        #pragma unroll
        for (int ct = 0; ct < 8; ++ct) {
            const short8_t b = bfr[(kk * 8 + ct) * 64 + l];
            acc[ct] = __builtin_amdgcn_mfma_f32_16x16x32_bf16(a, b, acc[ct], 0, 0, 0);
        }
    }

    #pragma unroll
    for (int ct = 0; ct < 8; ++ct) {
        const float b = b2[ct * 16 + lrow];
        #pragma unroll
        for (int r = 0; r < 4; ++r)
            s_c[wid][lk * 4 + r][ct * 16 + lrow] = acc[ct][r] + b;
    }
    __syncthreads();

    // coalesced store: wave region = 16 rows x 512 B contiguous (fp32)
    const float* reg = &s_c[wid][0][0];
    #pragma unroll
    for (int it = 0; it < 8; ++it) {
        const int off = it * 64 + l;            // 16B units, 0..511
        const long long row = mrow + (off >> 5);
        if (row < NN) {
            const float4 v = ((const float4*)reg)[off];
            *(float4*)(out + row * H + (off & 31) * 4) = v;
        }
    }
}

// ---------------------------------------------------------------------------
// Fallback path (tiny workspace): atomic scatter + simple MLP (all fp32).
// ---------------------------------------------------------------------------
__global__ __launch_bounds__(256) void scatter_kernel(
    const float* __restrict__ node_feat,
    const float* __restrict__ edge_feat,
    const int*   __restrict__ edge_src,
    const int*   __restrict__ edge_dst,
    float*       __restrict__ agg)
{
    long long tid = (long long)blockIdx.x * blockDim.x + threadIdx.x;
    const long long total = (long long)NE * 32;
    if (tid >= total) return;
    int e = (int)(tid >> 5);
    int q = (int)((tid & 31) << 2);
    int s = edge_src[e];
    int d = edge_dst[e];
    const float4 nf = *(const float4*)(node_feat + (long long)s * H + q);
    const float4 ef = *(const float4*)(edge_feat + (long long)e * H + q);
    float* dst = agg + (long long)d * H + q;
    atomicAdd(dst + 0, nf.x + ef.x);
    atomicAdd(dst + 1, nf.y + ef.y);
    atomicAdd(dst + 2, nf.z + ef.z);
    atomicAdd(dst + 3, nf.w + ef.w);
}

__global__ __launch_bounds__(256) void mlp_simple_kernel(
    const float* __restrict__ agg,
    const float* __restrict__ w1, const float* __restrict__ b1,
    const float* __restrict__ w2, const float* __restrict__ b2,
    float*       __restrict__ out)
{
    constexpr int NPB = 16;
    __shared__ float s_in[NPB][H];
    __shared__ float s_h [NPB][H2];
    const int t = threadIdx.x;
    const long long base = (long long)blockIdx.x * NPB;
    {
        const float4* src = (const float4*)(agg + base * H);
        float4* dst = (float4*)(&s_in[0][0]);
        dst[t]       = src[t];
        dst[t + 256] = src[t + 256];
    }
    __syncthreads();
    float acc[NPB];
    {
        const float b = b1[t];
        #pragma unroll
        for (int n = 0; n < NPB; ++n) acc[n] = b;
    }
    #pragma unroll 4
    for (int k = 0; k < H; ++k) {
        const float w = w1[k * H2 + t];
        #pragma unroll
        for (int n = 0; n < NPB; ++n) acc[n] = fmaf(s_in[n][k], w, acc[n]);
    }
    #pragma unroll
    for (int n = 0; n < NPB; ++n) s_h[n][t] = fmaxf(acc[n], 0.0f);
    __syncthreads();
    const int j = t & (H - 1);
    const int g = t >> 7;
    float acc2[NPB / 2];
    {
        const float b = b2[j];
        #pragma unroll
        for (int n = 0; n < NPB / 2; ++n) acc2[n] = b;
    }
    #pragma unroll 4
    for (int k = 0; k < H2; ++k) {
        const float w = w2[k * H + j];
        #pragma unroll
        for (int n = 0; n < NPB / 2; ++n)
            acc2[n] = fmaf(s_h[g * (NPB / 2) + n][k], w, acc2[n]);
    }
    #pragma unroll
    for (int n = 0; n < NPB / 2; ++n)
        out[(base + g * (NPB / 2) + n) * H + j] = acc2[n];
}

__global__ __launch_bounds__(256) void zero_agg_kernel(float4* __restrict__ p, int n4)
{
    int i = blockIdx.x * blockDim.x + threadIdx.x;
    if (i < n4) p[i] = make_float4(0.f, 0.f, 0.f, 0.f);
}

// ---------------------------------------------------------------------------
extern "C" void kernel_launch(void* const* d_in, const int* in_sizes, int n_in,
                              void* d_out, int out_size, void* d_ws, size_t ws_size,
                              hipStream_t stream)
{
    const float* node_feat = (const float*)d_in[0];
    const float* edge_feat = (const float*)d_in[1];
    const int*   edge_src  = (const int*)  d_in[2];
    const int*   edge_dst  = (const int*)  d_in[3];
    const float* w1 = (const float*)d_in[4];
    const float* b1 = (const float*)d_in[5];
    const float* w2 = (const float*)d_in[6];
    const float* b2 = (const float*)d_in[7];
    float* out = (float*)d_out;

    const int NB = (NN + 255) / 256;            // 196 scan blocks

    // Workspace layout (256-B aligned regions)
    const size_t count_b  = ((size_t)NN * 4 + 255) & ~(size_t)255;        // 200 KB
    const size_t cursor_b = count_b;                                       // 200 KB
    const size_t offs_b   = (((size_t)NN + 1) * 4 + 255) & ~(size_t)255;   // 200 KB
    const size_t bsum_b   = ((size_t)NB * 4 + 255) & ~(size_t)255;         // 1 KB
    const size_t bexc_b   = bsum_b;                                        // 1 KB
    const size_t es_b     = ((size_t)NE * 8 + 255) & ~(size_t)255;         // 6.4 MB
    const size_t w1p_b    = (size_t)32768 * 2;                             // 64 KB
    const size_t w2p_b    = (size_t)32768 * 2;                             // 64 KB
    const size_t aggb_b   = ((size_t)NN * H * 2 + 255) & ~(size_t)255;     // 12.8 MB
    const size_t hb_b     = ((size_t)NN * H2 * 2 + 255) & ~(size_t)255;    // 25.6 MB
    const size_t need     = count_b + cursor_b + offs_b + bsum_b + bexc_b
                          + es_b + w1p_b + w2p_b + aggb_b + hb_b;          // ~46 MB

    if (ws_size >= need) {
        char* p = (char*)d_ws;
        int*   count     = (int*)p;              p += count_b;
        int*   cursor    = (int*)p;              p += cursor_b;
        int*   offsets   = (int*)p;              p += offs_b;
        int*   bsum      = (int*)p;              p += bsum_b;
        int*   bexc      = (int*)p;              p += bexc_b;
        int2*  sorted_es = (int2*)p;             p += es_b;
        short* w1p       = (short*)p;            p += w1p_b;
        short* w2p       = (short*)p;            p += w2p_b;
        short* aggb      = (short*)p;            p += aggb_b;
        short* hb        = (short*)p;

        {
            const int n4 = (int)((count_b + cursor_b) / 16);
            zero_kernel<<<(n4 + 255) / 256, 256, 0, stream>>>((int4*)d_ws, n4);
        }

        const int eb = 256, eg = (NE + eb - 1) / eb;   // 3125
        count_kernel<<<eg, eb, 0, stream>>>(edge_dst, count);
        scan1_kernel<<<NB, 256, 0, stream>>>(count, bsum);
        scan2_kernel<<<1, 256, 0, stream>>>(bsum, bexc, NB);
        scan3_kernel<<<NB, 256, 0, stream>>>(count, bexc, offsets);
        place_kernel<<<eg, eb, 0, stream>>>(edge_dst, edge_src, offsets, cursor, sorted_es);
        pack_kernel<<<128, 256, 0, stream>>>(w1, w2, w1p, w2p);
        gather_kernel<<<NN / 4, 256, 0, stream>>>(
            node_feat, edge_feat, sorted_es, offsets, aggb);
        const int gemm_grid = (NN + 63) / 64;          // 782
        l1_kernel<<<gemm_grid, 256, 0, stream>>>(aggb, w1p, b1, hb);
        l2_kernel<<<gemm_grid, 256, 0, stream>>>(hb, w2p, b2, out);
    } else {
        // Fallback: atomic path + simple fp32 MLP
        const size_t agg_bytes = (size_t)NN * H * sizeof(float);
        float* agg = (ws_size >= agg_bytes) ? (float*)d_ws : out;
        {
            const int n4 = (int)(agg_bytes / 16);
            zero_agg_kernel<<<(n4 + 255) / 256, 256, 0, stream>>>((float4*)agg, n4);
        }
        const long long total = (long long)NE * 32;
        const int block = 256;
        const int grid  = (int)((total + block - 1) / block);
        scatter_kernel<<<grid, block, 0, stream>>>(
            node_feat, edge_feat, edge_src, edge_dst, agg);
        mlp_simple_kernel<<<NN / 16, 256, 0, stream>>>(agg, w1, b1, w2, b2, out);
    }
}